// Round 8
// baseline (304.884 us; speedup 1.0000x reference)
//
#include <hip/hip_runtime.h>
#include <hip/hip_fp16.h>
#include <math.h>

#define WAVE  64
#define SPAD  128    // padded score cols (K=100 -> 128; cols 100..127 are exact zeros)
#define NW    8      // waves per block in k_fused
#define NGEMM 2048   // GEMM blocks in k_prep

typedef float    f32x4 __attribute__((ext_vector_type(4)));
typedef _Float16 h2    __attribute__((ext_vector_type(2)));
typedef _Float16 h4    __attribute__((ext_vector_type(4)));

__device__ __forceinline__ h2 mkh2(_Float16 a, _Float16 b) { h2 r; r[0] = a; r[1] = b; return r; }

// dot2: fp16 pair multiply, fp32 accumulate (V_DOT2_F32_F16); scalar fallback
__device__ __forceinline__ float fdot2f(h2 a, h2 b, float c) {
#if __has_builtin(__builtin_amdgcn_fdot2)
    return __builtin_amdgcn_fdot2(a, b, c, false);
#else
    return c + (float)a[0] * (float)b[0] + (float)a[1] * (float)b[1];
#endif
}

// fp32 convert-and-accumulate of one 16B chunk (8 halves), weighted
#define ACC8T(qq,s,A0,A1,A2,A3,A4,A5,A6,A7) {                                \
    const __half2* hh_ = (const __half2*)&(qq);                              \
    float2 f0_=__half22float2(hh_[0]), f1_=__half22float2(hh_[1]);           \
    float2 f2_=__half22float2(hh_[2]), f3_=__half22float2(hh_[3]);           \
    A0+=(s)*f0_.x; A1+=(s)*f0_.y; A2+=(s)*f1_.x; A3+=(s)*f1_.y;              \
    A4+=(s)*f2_.x; A5+=(s)*f2_.y; A6+=(s)*f3_.x; A7+=(s)*f3_.y; }

// depth-1 fp16 pair-add over 2 token-rows, then one fp32 convert-add
#define TREE2T(qa,qb,A0,A1,A2,A3,A4,A5,A6,A7) {                              \
    const __half2* p0_ = (const __half2*)&(qa);                              \
    const __half2* p1_ = (const __half2*)&(qb);                              \
    __half2 s0_=__hadd2(p0_[0],p1_[0]);                                      \
    __half2 s1_=__hadd2(p0_[1],p1_[1]);                                      \
    __half2 s2_=__hadd2(p0_[2],p1_[2]);                                      \
    __half2 s3_=__hadd2(p0_[3],p1_[3]);                                      \
    float2 f0_=__half22float2(s0_), f1_=__half22float2(s1_);                 \
    float2 f2_=__half22float2(s2_), f3_=__half22float2(s3_);                 \
    A0+=f0_.x; A1+=f0_.y; A2+=f1_.x; A3+=f1_.y;                              \
    A4+=f2_.x; A5+=f2_.y; A6+=f3_.x; A7+=f3_.y; }

// ---- quarter-group (16-lane) S-row gather steps: 4 tokens per wave-load ----
// 8 tokens = 2 independent loads, fp16 pair-tree
#define QSTEP2(idxv,j0,A0,A1,A2,A3,A4,A5,A6,A7) {                            \
    int r0_ = __shfl(idxv, (j0) + qtr);                                      \
    int r1_ = __shfl(idxv, (j0) + 4 + qtr);                                  \
    float4 q0_ = S16[(size_t)r0_ * 16 + c];                                  \
    float4 q1_ = S16[(size_t)r1_ * 16 + c];                                  \
    TREE2T(q0_, q1_, A0,A1,A2,A3,A4,A5,A6,A7); }
// 4 tokens = 1 load, direct fp32 accumulate
#define QSTEP1(idxv,j0,A0,A1,A2,A3,A4,A5,A6,A7) {                            \
    int r0_ = __shfl(idxv, (j0) + qtr);                                      \
    float4 q0_ = S16[(size_t)r0_ * 16 + c];                                  \
    ACC8T(q0_, 1.0f, A0,A1,A2,A3,A4,A5,A6,A7); }
// tail 1..3 tokens (weight-0 clamp for missing quarters)
#define QTAIL(idxv,jv,nn,A0,A1,A2,A3,A4,A5,A6,A7) if ((jv) < (nn)) {         \
    int srcl_ = (jv) + qtr;                                                  \
    int rr_ = __shfl(idxv, (srcl_ < (nn)) ? srcl_ : ((nn) - 1));             \
    float s_ = (srcl_ < (nn)) ? 1.0f : 0.0f;                                 \
    float4 q_ = S16[(size_t)rr_ * 16 + c];                                   \
    ACC8T(q_, s_, A0,A1,A2,A3,A4,A5,A6,A7); }

// quarter-merge (xor 16,32) + mean
#define QFIN(A0,A1,A2,A3,A4,A5,A6,A7,nv) {                                   \
    A0+=__shfl_xor(A0,16); A1+=__shfl_xor(A1,16);                            \
    A2+=__shfl_xor(A2,16); A3+=__shfl_xor(A3,16);                            \
    A4+=__shfl_xor(A4,16); A5+=__shfl_xor(A5,16);                            \
    A6+=__shfl_xor(A6,16); A7+=__shfl_xor(A7,16);                            \
    A0+=__shfl_xor(A0,32); A1+=__shfl_xor(A1,32);                            \
    A2+=__shfl_xor(A2,32); A3+=__shfl_xor(A3,32);                            \
    A4+=__shfl_xor(A4,32); A5+=__shfl_xor(A5,32);                            \
    A6+=__shfl_xor(A6,32); A7+=__shfl_xor(A7,32);                            \
    float inv_ = 1.0f/(float)(nv);                                           \
    A0*=inv_; A1*=inv_; A2*=inv_; A3*=inv_;                                  \
    A4*=inv_; A5*=inv_; A6*=inv_; A7*=inv_; }

// selected score = mean-S-row[rt] (one element pick + 16-lane reduce)
#define SELP(A0,A1,A2,A3,A4,A5,A6,A7,pvar) {                                 \
    float t_ = (rlo==0)?A0:(rlo==1)?A1:(rlo==2)?A2:(rlo==3)?A3:              \
               (rlo==4)?A4:(rlo==5)?A5:(rlo==6)?A6:A7;                       \
    pvar = (c == rhi) ? t_ : 0.0f;                                           \
    pvar += __shfl_xor(pvar,1); pvar += __shfl_xor(pvar,2);                  \
    pvar += __shfl_xor(pvar,4); pvar += __shfl_xor(pvar,8); }

// online-softmax update of (mx,sum,z0..z7)
#define ONLUPD(pv,A0,A1,A2,A3,A4,A5,A6,A7) {                                 \
    float nmx_=fmaxf(mx,pv);                                                 \
    float sc_=__expf(mx-nmx_), w_=__expf((pv)-nmx_);                         \
    sum=sum*sc_+w_;                                                          \
    z0=z0*sc_+w_*A0; z1=z1*sc_+w_*A1; z2=z2*sc_+w_*A2; z3=z3*sc_+w_*A3;      \
    z4=z4*sc_+w_*A4; z5=z5*sc_+w_*A5; z6=z6*sc_+w_*A6; z7=z7*sc_+w_*A7;      \
    mx=nmx_; }

// ---------------------------------------------------------------------------
// K1 (prep), grid sections:
//  [0, nArgBlk):  type_idx[b] = argmax_k typeTensor[b*K+k]       (wave/bag)
//  [+, NGEMM):    S = we @ W^T, fp16, [V][SPAD]; cols K..SPAD-1 = 0
// The S-factorization replaces BOTH the fp16 table conversion AND k_fused's
// final projection: out[b] = sum_m att_m * mean_t S[tok_t,:] (exact identity,
// all downstream ops are linear in token embeddings). Gather bytes halve
// (512B emb row -> 256B S row), since the gather is BW-bound at ~4 TB/s (R6).
// GEMM: W^T staged in LDS kpair-major per col (wcp[col][kp], pad 130 -> b64
// reads 2-way-conflict-free); 4 rows/wave, B-frags reused across rows;
// fp32 accumulation via v_dot2_f32_f16.
// ---------------------------------------------------------------------------
__global__ __launch_bounds__(256) void k_prep(const float* __restrict__ tt,
                                              const float* __restrict__ lw,
                                              const float* __restrict__ we,
                                              int* __restrict__ type_idx,
                                              __half* __restrict__ S,
                                              int B, int K, int D, int V,
                                              int nArgBlk) {
    __shared__ __half2 wcp[100][130];    // [col][kpair]  (K=100, D/2=128 kpairs)
    __shared__ __half2 arow[4][4][128];  // per-wave 4-row staging

    int bx = blockIdx.x;
    if (bx < nArgBlk) {
        int wid  = threadIdx.x >> 6;
        int lane = threadIdx.x & 63;
        int b = bx * 4 + wid;
        if (b >= B) return;
        float best = -INFINITY;
        int   bi   = 0x7fffffff;
        for (int k = lane; k < K; k += WAVE) {
            float v = tt[(size_t)b * K + k];
            if (v > best) { best = v; bi = k; }
        }
        for (int off = 32; off > 0; off >>= 1) {
            float ov = __shfl_down(best, off);
            int   oi = __shfl_down(bi, off);
            if (ov > best || (ov == best && oi < bi)) { best = ov; bi = oi; }
        }
        if (lane == 0) type_idx[b] = bi;
        return;
    }

    // ---- GEMM section ----
    int gb   = bx - nArgBlk;
    int tid  = threadIdx.x;
    int wid  = tid >> 6;
    int lane = tid & 63;
    int KH   = K >> 1;                 // 50

    // stage W^T: wcp[col][kp] = (W[col][2kp], W[col][2kp+1])
    int kp2 = D >> 1;                  // 128
    for (int i = tid; i < K * kp2; i += 256) {
        int col = i >> 7;
        int kp  = i & 127;
        float w0 = lw[(size_t)col * D + 2 * kp];
        float w1 = lw[(size_t)col * D + 2 * kp + 1];
        wcp[col][kp] = __halves2half2(__float2half(w0), __float2half(w1));
    }
    __syncthreads();

    int c0 = (lane < KH) ? lane : (KH - 2);   // lanes >= KH duplicate (benign)
    int c1 = c0 + KH;

    for (int base = gb * 16; base < V; base += NGEMM * 16) {
        int rb = base + wid * 4;
        // stage 4 rows of we (fp32 -> fp16), 1KB coalesced load per row
        #pragma unroll
        for (int i = 0; i < 4; ++i) {
            int r = rb + i;
            f32x4 av = {0.f, 0.f, 0.f, 0.f};
            if (r < V)
                av = __builtin_nontemporal_load((const f32x4*)we + (size_t)r * 64 + lane);
            arow[wid][i][2*lane]   = __halves2half2(__float2half(av.x), __float2half(av.y));
            arow[wid][i][2*lane+1] = __halves2half2(__float2half(av.z), __float2half(av.w));
        }

        float acc[4][2] = {{0.f,0.f},{0.f,0.f},{0.f,0.f},{0.f,0.f}};
        for (int g = 0; g < 16; ++g) {        // 16 k per group
            int kb = g * 8;                   // kpair base
            h4 b0[4], b1[4];
            #pragma unroll
            for (int t = 0; t < 4; ++t) {
                b0[t] = *(const h4*)&wcp[c0][kb + 2*t];
                b1[t] = *(const h4*)&wcp[c1][kb + 2*t];
            }
            #pragma unroll
            for (int i = 0; i < 4; ++i) {
                #pragma unroll
                for (int t = 0; t < 4; ++t) {
                    h4 a = *(const h4*)&arow[wid][i][kb + 2*t];   // uniform bcast
                    h2 alo = mkh2(a[0], a[1]);
                    h2 ahi = mkh2(a[2], a[3]);
                    acc[i][0] = fdot2f(alo, mkh2(b0[t][0], b0[t][1]), acc[i][0]);
                    acc[i][0] = fdot2f(ahi, mkh2(b0[t][2], b0[t][3]), acc[i][0]);
                    acc[i][1] = fdot2f(alo, mkh2(b1[t][0], b1[t][1]), acc[i][1]);
                    acc[i][1] = fdot2f(ahi, mkh2(b1[t][2], b1[t][3]), acc[i][1]);
                }
            }
        }

        #pragma unroll
        for (int i = 0; i < 4; ++i) {
            int r = rb + i;
            if (r < V) {
                if (lane < KH) {
                    ((__half*)S)[(size_t)r * SPAD + c0] = __float2half(acc[i][0]);
                    ((__half*)S)[(size_t)r * SPAD + c1] = __float2half(acc[i][1]);
                } else {
                    // lanes 50..63 zero the pad cols 100..127 (half2 idx 50..63)
                    ((__half2*)S)[(size_t)r * (SPAD/2) + lane] =
                        __halves2half2(__float2half(0.f), __float2half(0.f));
                }
            }
        }
    }
}

// ---------------------------------------------------------------------------
// K2 (fused): one block (512 thr = 8 waves) per bag; each wave owns TWO
// adjacent mention chains (16 chains/bag, zero divergence, wave-uniform
// control). Gathers 256B S-rows (quarter-group: 4 tokens per wave-load).
// sel[m] = mean-S-row[type_idx[b]] (one-hot pick). out[b] = normalized
// online-softmax accumulation of mean-S-rows -- NO final projection.
// ---------------------------------------------------------------------------
__global__ __launch_bounds__(512, 8) void k_fused(const int* __restrict__ fs,
                                                  const int* __restrict__ offs,
                                                  const int* __restrict__ scope,
                                                  const int* __restrict__ type_idx,
                                                  const __half* __restrict__ S,
                                                  float* __restrict__ out,
                                                  int B, int M, int T, int K) {
    __shared__ float s_acc[NW][SPAD];
    __shared__ float s_stats[NW][2];
    __shared__ float s_be[SPAD];

    int b    = blockIdx.x;
    int tid  = threadIdx.x;
    int wid  = tid >> 6;
    int lane = tid & 63;
    int c    = lane & 15;     // 16B chunk within 256B S-row
    int qtr  = lane >> 4;     // quarter: token j+qtr of each 4-token step

    int m0 = scope[b];
    int m1 = scope[b + 1];
    int rt  = type_idx[b];
    int rhi = rt >> 3, rlo = rt & 7;

    const float4* S16 = (const float4*)S;   // 16 chunks per 256B row

    float mx = -INFINITY, sum = 0.f;
    float z0=0,z1=0,z2=0,z3=0,z4=0,z5=0,z6=0,z7=0;

    for (int mA = m0 + wid * 2; mA < m1; mA += 2 * NW) {
        int mB = mA + 1;
        bool hasB = (mB < m1);                  // wave-uniform

        int tA0 = offs[mA];
        int tA1 = (mA + 1 < M) ? offs[mA + 1] : T;
        int tB0 = tA1;                          // offs[mB] == tA1 when hasB
        int tB1 = hasB ? ((mB + 1 < M) ? offs[mB + 1] : T) : tA1;

        int nA = tA1 - tA0;
        int nB = tB1 - tB0;                     // 0 when !hasB

        float aA0=0,aA1=0,aA2=0,aA3=0,aA4=0,aA5=0,aA6=0,aA7=0;
        float aB0=0,aB1=0,aB2=0,aB3=0,aB4=0,aB5=0,aB6=0,aB7=0;

        int cA = tA0, cB = tB0;
        while (cA < tA1 || cB < tB1) {
            int nnA = tA1 - cA; nnA = (nnA > 64) ? 64 : nnA; if (nnA < 0) nnA = 0;
            int nnB = tB1 - cB; nnB = (nnB > 64) ? 64 : nnB; if (nnB < 0) nnB = 0;
            int idxA = (lane < nnA) ? fs[cA + lane] : 0;
            int idxB = (lane < nnB) ? fs[cB + lane] : 0;

            int jA = 0, jB = 0;
            for (; jA + 8 <= nnA && jB + 8 <= nnB; jA += 8, jB += 8) {
                QSTEP2(idxA, jA, aA0,aA1,aA2,aA3,aA4,aA5,aA6,aA7);
                QSTEP2(idxB, jB, aB0,aB1,aB2,aB3,aB4,aB5,aB6,aB7);
            }
            for (; jA + 8 <= nnA; jA += 8)
                QSTEP2(idxA, jA, aA0,aA1,aA2,aA3,aA4,aA5,aA6,aA7);
            for (; jB + 8 <= nnB; jB += 8)
                QSTEP2(idxB, jB, aB0,aB1,aB2,aB3,aB4,aB5,aB6,aB7);
            for (; jA + 4 <= nnA; jA += 4)
                QSTEP1(idxA, jA, aA0,aA1,aA2,aA3,aA4,aA5,aA6,aA7);
            for (; jB + 4 <= nnB; jB += 4)
                QSTEP1(idxB, jB, aB0,aB1,aB2,aB3,aB4,aB5,aB6,aB7);
            QTAIL(idxA, jA, nnA, aA0,aA1,aA2,aA3,aA4,aA5,aA6,aA7);
            QTAIL(idxB, jB, nnB, aB0,aB1,aB2,aB3,aB4,aB5,aB6,aB7);
            cA += nnA; cB += nnB;
        }

        // epilogue: quarter-merge + mean + one-hot score + online update
        {
            QFIN(aA0,aA1,aA2,aA3,aA4,aA5,aA6,aA7, nA);
            float pA; SELP(aA0,aA1,aA2,aA3,aA4,aA5,aA6,aA7, pA);
            ONLUPD(pA, aA0,aA1,aA2,aA3,aA4,aA5,aA6,aA7);
        }
        if (hasB) {
            QFIN(aB0,aB1,aB2,aB3,aB4,aB5,aB6,aB7, nB);
            float pB; SELP(aB0,aB1,aB2,aB3,aB4,aB5,aB6,aB7, pB);
            ONLUPD(pB, aB0,aB1,aB2,aB3,aB4,aB5,aB6,aB7);
        }
    }

    // ---- deposit per-wave state (lanes 0..15 own dims 8c..8c+7) ----
    if (lane < 16) {
        ((float4*)s_acc[wid])[c * 2]     = make_float4(z0, z1, z2, z3);
        ((float4*)s_acc[wid])[c * 2 + 1] = make_float4(z4, z5, z6, z7);
    }
    if (lane == 0) { s_stats[wid][0] = mx; s_stats[wid][1] = sum; }
    __syncthreads();

    // ---- 8-way online-softmax merge; one S-col per thread (tid<SPAD) ----
    if (tid < SPAD) {
        float Mx = -INFINITY;
        #pragma unroll
        for (int g = 0; g < NW; ++g) Mx = fmaxf(Mx, s_stats[g][0]);
        float Ssum = 0.f, be = 0.f;
        #pragma unroll
        for (int g = 0; g < NW; ++g) {
            float e = __expf(s_stats[g][0] - Mx);
            Ssum += s_stats[g][1] * e;
            be   += s_acc[g][tid] * e;
        }
        s_be[tid] = be * (1.0f / Ssum);
    }
    __syncthreads();

    // ---- output: out[b][k] = s_be[k], k < K (no projection!) ----
    float* ob = out + (size_t)b * K;
    if (2 * tid + 1 < K) {
        ((float2*)ob)[tid] = make_float2(s_be[2*tid], s_be[2*tid+1]);
    } else if (2 * tid < K) {
        ob[2*tid] = s_be[2*tid];
    }
}

// ---------------------------------------------------------------------------
extern "C" void kernel_launch(void* const* d_in, const int* in_sizes, int n_in,
                              void* d_out, int out_size, void* d_ws, size_t ws_size,
                              hipStream_t stream) {
    const int*   feature_seq = (const int*)d_in[0];
    const int*   offset_seq  = (const int*)d_in[1];
    const int*   scope       = (const int*)d_in[2];
    const float* typeTensor  = (const float*)d_in[3];
    const float* word_emb    = (const float*)d_in[4];
    const float* linear_w    = (const float*)d_in[5];
    float* out = (float*)d_out;

    const int T = in_sizes[0];
    const int M = in_sizes[1];
    const int B = in_sizes[2] - 1;
    const int K = in_sizes[3] / B;       // 100
    const int D = in_sizes[5] / K;       // 256
    const int V = in_sizes[4] / D;       // 100000

    // workspace carve-up: type_idx + S (V * SPAD halves = 25.6 MB)
    char* w = (char*)d_ws;
    auto align256 = [](size_t x) { return (x + 255) & ~(size_t)255; };
    int*    type_idx = (int*)w;    w += align256((size_t)B * sizeof(int));
    __half* S        = (__half*)w; // V * SPAD halves

    // K1: argmax + S-GEMM
    {
        int nArgBlk = (B + 3) / 4;
        k_prep<<<nArgBlk + NGEMM, 256, 0, stream>>>(
            typeTensor, linear_w, word_emb, type_idx, S, B, K, D, V, nArgBlk);
    }
    // K2: fused mention mean-S + per-bag online softmax (direct K-dim output)
    {
        k_fused<<<B, 512, 0, stream>>>(feature_seq, offset_seq, scope, type_idx,
                                       S, out, B, M, T, K);
    }
}

// Round 9
// 254.670 us; speedup vs baseline: 1.1972x; 1.1972x over previous
//
#include <hip/hip_runtime.h>
#include <hip/hip_fp16.h>
#include <math.h>

#define WAVE  64
#define SPAD  128    // padded score cols (K=100 -> 128)
#define NW    8      // waves per block in k_fused
#define BPADK 264    // LDS k-stride for W^T (256 + 8 pad halves)

typedef float    f32x4 __attribute__((ext_vector_type(4)));
typedef _Float16 f16x8 __attribute__((ext_vector_type(8)));

// fp32 convert-and-accumulate of one 16B chunk (8 halves), weighted
#define ACC8T(qq,s,A0,A1,A2,A3,A4,A5,A6,A7) {                                \
    const __half2* hh_ = (const __half2*)&(qq);                              \
    float2 f0_=__half22float2(hh_[0]), f1_=__half22float2(hh_[1]);           \
    float2 f2_=__half22float2(hh_[2]), f3_=__half22float2(hh_[3]);           \
    A0+=(s)*f0_.x; A1+=(s)*f0_.y; A2+=(s)*f1_.x; A3+=(s)*f1_.y;              \
    A4+=(s)*f2_.x; A5+=(s)*f2_.y; A6+=(s)*f3_.x; A7+=(s)*f3_.y; }

// depth-1 fp16 pair-add over 2 token-rows, then one fp32 convert-add
#define TREE2T(qa,qb,A0,A1,A2,A3,A4,A5,A6,A7) {                              \
    const __half2* p0_ = (const __half2*)&(qa);                              \
    const __half2* p1_ = (const __half2*)&(qb);                              \
    __half2 s0_=__hadd2(p0_[0],p1_[0]);                                      \
    __half2 s1_=__hadd2(p0_[1],p1_[1]);                                      \
    __half2 s2_=__hadd2(p0_[2],p1_[2]);                                      \
    __half2 s3_=__hadd2(p0_[3],p1_[3]);                                      \
    float2 f0_=__half22float2(s0_), f1_=__half22float2(s1_);                 \
    float2 f2_=__half22float2(s2_), f3_=__half22float2(s3_);                 \
    A0+=f0_.x; A1+=f0_.y; A2+=f1_.x; A3+=f1_.y;                              \
    A4+=f2_.x; A5+=f2_.y; A6+=f3_.x; A7+=f3_.y; }

// ---- quarter-group (16-lane) S-row gather steps: 4 tokens per wave-load ----
#define QSTEP2(idxv,j0,A0,A1,A2,A3,A4,A5,A6,A7) {                            \
    int r0_ = __shfl(idxv, (j0) + qtr);                                      \
    int r1_ = __shfl(idxv, (j0) + 4 + qtr);                                  \
    float4 q0_ = S16[(size_t)r0_ * 16 + c];                                  \
    float4 q1_ = S16[(size_t)r1_ * 16 + c];                                  \
    TREE2T(q0_, q1_, A0,A1,A2,A3,A4,A5,A6,A7); }
#define QSTEP1(idxv,j0,A0,A1,A2,A3,A4,A5,A6,A7) {                            \
    int r0_ = __shfl(idxv, (j0) + qtr);                                      \
    float4 q0_ = S16[(size_t)r0_ * 16 + c];                                  \
    ACC8T(q0_, 1.0f, A0,A1,A2,A3,A4,A5,A6,A7); }
#define QTAIL(idxv,jv,nn,A0,A1,A2,A3,A4,A5,A6,A7) if ((jv) < (nn)) {         \
    int srcl_ = (jv) + qtr;                                                  \
    int rr_ = __shfl(idxv, (srcl_ < (nn)) ? srcl_ : ((nn) - 1));             \
    float s_ = (srcl_ < (nn)) ? 1.0f : 0.0f;                                 \
    float4 q_ = S16[(size_t)rr_ * 16 + c];                                   \
    ACC8T(q_, s_, A0,A1,A2,A3,A4,A5,A6,A7); }

// quarter-merge (xor 16,32) + mean
#define QFIN(A0,A1,A2,A3,A4,A5,A6,A7,nv) {                                   \
    A0+=__shfl_xor(A0,16); A1+=__shfl_xor(A1,16);                            \
    A2+=__shfl_xor(A2,16); A3+=__shfl_xor(A3,16);                            \
    A4+=__shfl_xor(A4,16); A5+=__shfl_xor(A5,16);                            \
    A6+=__shfl_xor(A6,16); A7+=__shfl_xor(A7,16);                            \
    A0+=__shfl_xor(A0,32); A1+=__shfl_xor(A1,32);                            \
    A2+=__shfl_xor(A2,32); A3+=__shfl_xor(A3,32);                            \
    A4+=__shfl_xor(A4,32); A5+=__shfl_xor(A5,32);                            \
    A6+=__shfl_xor(A6,32); A7+=__shfl_xor(A7,32);                            \
    float inv_ = 1.0f/(float)(nv);                                           \
    A0*=inv_; A1*=inv_; A2*=inv_; A3*=inv_;                                  \
    A4*=inv_; A5*=inv_; A6*=inv_; A7*=inv_; }

// selected score = mean-S-row[rt] (one element pick + 16-lane reduce)
#define SELP(A0,A1,A2,A3,A4,A5,A6,A7,pvar) {                                 \
    float t_ = (rlo==0)?A0:(rlo==1)?A1:(rlo==2)?A2:(rlo==3)?A3:              \
               (rlo==4)?A4:(rlo==5)?A5:(rlo==6)?A6:A7;                       \
    pvar = (c == rhi) ? t_ : 0.0f;                                           \
    pvar += __shfl_xor(pvar,1); pvar += __shfl_xor(pvar,2);                  \
    pvar += __shfl_xor(pvar,4); pvar += __shfl_xor(pvar,8); }

// online-softmax update of (mx,sum,z0..z7)
#define ONLUPD(pv,A0,A1,A2,A3,A4,A5,A6,A7) {                                 \
    float nmx_=fmaxf(mx,pv);                                                 \
    float sc_=__expf(mx-nmx_), w_=__expf((pv)-nmx_);                         \
    sum=sum*sc_+w_;                                                          \
    z0=z0*sc_+w_*A0; z1=z1*sc_+w_*A1; z2=z2*sc_+w_*A2; z3=z3*sc_+w_*A3;      \
    z4=z4*sc_+w_*A4; z5=z5*sc_+w_*A5; z6=z6*sc_+w_*A6; z7=z7*sc_+w_*A7;      \
    mx=nmx_; }

// ---------------------------------------------------------------------------
// K1 (prep), grid sections:
//  [0, nArgBlk):  type_idx[b] = argmax_k typeTensor[b*K+k]       (wave/bag)
//  [+, nGemmBlk): S = we @ W^T fp16 [V][SPAD] via MFMA 16x16x32_f16.
// R8's dot2 GEMM was VALU-bound at 131us (44% VALUBusy, 19% occ) vs a
// ~20us HBM floor (we 102.4MB + S 25.6MB). MFMA version: W^T staged once
// per block in LDS fp16 [112][BPADK] (264-pad: b128 reads 2-way ~free);
// A-frags straight from we -- one wave-load covers 16 rows x 128B
// contiguous (full coalescing); 56 MFMA per 16-row strip, acc 28 VGPR.
// A and B frags use the SAME (lane-group->k) map, so the k-contraction is
// correct under any internal k-permutation; C/D map is the m89-verified
// col=lane&15, row=(lane>>4)*4+reg.
// ---------------------------------------------------------------------------
__global__ __launch_bounds__(256) void k_prep(const float* __restrict__ tt,
                                              const float* __restrict__ lw,
                                              const float* __restrict__ we,
                                              int* __restrict__ type_idx,
                                              __half* __restrict__ S,
                                              int B, int K, int D, int V,
                                              int nArgBlk) {
    __shared__ _Float16 lwh[112 * BPADK];   // 59,136 B

    int bx = blockIdx.x;
    if (bx < nArgBlk) {
        int wid  = threadIdx.x >> 6;
        int lane = threadIdx.x & 63;
        int b = bx * 4 + wid;
        if (b >= B) return;
        float best = -INFINITY;
        int   bi   = 0x7fffffff;
        for (int k = lane; k < K; k += WAVE) {
            float v = tt[(size_t)b * K + k];
            if (v > best) { best = v; bi = k; }
        }
        for (int off = 32; off > 0; off >>= 1) {
            float ov = __shfl_down(best, off);
            int   oi = __shfl_down(bi, off);
            if (ov > best || (ov == best && oi < bi)) { best = ov; bi = oi; }
        }
        if (lane == 0) type_idx[b] = bi;
        return;
    }

    // ---- MFMA GEMM section ----
    int tid  = threadIdx.x;
    int wid  = tid >> 6;
    int lane = tid & 63;

    // stage W^T -> lwh[col][k] fp16; cols K..111 zero (pad col-tiles)
    for (int i4 = tid; i4 < 112 * 64; i4 += 256) {
        int col = i4 >> 6;
        int k4  = (i4 & 63) << 2;
        float4 v = make_float4(0.f, 0.f, 0.f, 0.f);
        if (col < K) v = ((const float4*)lw)[(size_t)col * 64 + (k4 >> 2)];
        _Float16* dst = &lwh[col * BPADK + k4];
        dst[0] = (_Float16)v.x; dst[1] = (_Float16)v.y;
        dst[2] = (_Float16)v.z; dst[3] = (_Float16)v.w;
    }
    __syncthreads();

    int strip = (bx - nArgBlk) * 4 + wid;   // 16-row strip
    int rbase = strip * 16;
    if (rbase < V) {                        // V = 100000 = 6250*16 exactly
        int r16  = lane & 15;               // A row / B col within tile
        int kgrp = (lane >> 4) * 8;         // my 8-k group within 32-chunk

        const float4* weB = (const float4*)(we + (size_t)(rbase + r16) * 256);

        f32x4 acc[7];
        #pragma unroll
        for (int ct = 0; ct < 7; ++ct) acc[ct] = (f32x4){0.f, 0.f, 0.f, 0.f};

        #pragma unroll
        for (int kc = 0; kc < 8; ++kc) {
            int kb = kc * 32 + kgrp;
            float4 a0 = weB[kb >> 2];
            float4 a1 = weB[(kb >> 2) + 1];
            f16x8 af;
            af[0]=(_Float16)a0.x; af[1]=(_Float16)a0.y;
            af[2]=(_Float16)a0.z; af[3]=(_Float16)a0.w;
            af[4]=(_Float16)a1.x; af[5]=(_Float16)a1.y;
            af[6]=(_Float16)a1.z; af[7]=(_Float16)a1.w;
            #pragma unroll
            for (int ct = 0; ct < 7; ++ct) {
                f16x8 bf = *(const f16x8*)&lwh[(ct * 16 + r16) * BPADK + kb];
                acc[ct] = __builtin_amdgcn_mfma_f32_16x16x32_f16(af, bf, acc[ct], 0, 0, 0);
            }
        }

        // write S: lane covers rows rbase+(lane>>4)*4+i, col ct*16+(lane&15)
        int rofs = (lane >> 4) * 4;
        #pragma unroll
        for (int ct = 0; ct < 7; ++ct) {
            #pragma unroll
            for (int i = 0; i < 4; ++i)
                S[(size_t)(rbase + rofs + i) * SPAD + ct * 16 + r16] =
                    __float2half(acc[ct][i]);
        }
        #pragma unroll
        for (int i = 0; i < 4; ++i)      // zero pad cols 112..127
            S[(size_t)(rbase + rofs + i) * SPAD + 112 + r16] = __half(0.0f);
    }
}

// ---------------------------------------------------------------------------
// K2 (fused): UNCHANGED from round 8 (measured ~54us). One block (512 thr =
// 8 waves) per bag; wave owns two adjacent mention chains (16 chains/bag,
// zero divergence). Gathers 256B S-rows (quarter-group: 4 tokens/wave-load).
// sel = one-hot pick from mean-S-row; out = online-softmax accumulation of
// mean-S-rows -- no final projection.
// ---------------------------------------------------------------------------
__global__ __launch_bounds__(512, 8) void k_fused(const int* __restrict__ fs,
                                                  const int* __restrict__ offs,
                                                  const int* __restrict__ scope,
                                                  const int* __restrict__ type_idx,
                                                  const __half* __restrict__ S,
                                                  float* __restrict__ out,
                                                  int B, int M, int T, int K) {
    __shared__ float s_acc[NW][SPAD];
    __shared__ float s_stats[NW][2];
    __shared__ float s_be[SPAD];

    int b    = blockIdx.x;
    int tid  = threadIdx.x;
    int wid  = tid >> 6;
    int lane = tid & 63;
    int c    = lane & 15;     // 16B chunk within 256B S-row
    int qtr  = lane >> 4;     // quarter: token j+qtr of each 4-token step

    int m0 = scope[b];
    int m1 = scope[b + 1];
    int rt  = type_idx[b];
    int rhi = rt >> 3, rlo = rt & 7;

    const float4* S16 = (const float4*)S;   // 16 chunks per 256B row

    float mx = -INFINITY, sum = 0.f;
    float z0=0,z1=0,z2=0,z3=0,z4=0,z5=0,z6=0,z7=0;

    for (int mA = m0 + wid * 2; mA < m1; mA += 2 * NW) {
        int mB = mA + 1;
        bool hasB = (mB < m1);                  // wave-uniform

        int tA0 = offs[mA];
        int tA1 = (mA + 1 < M) ? offs[mA + 1] : T;
        int tB0 = tA1;                          // offs[mB] == tA1 when hasB
        int tB1 = hasB ? ((mB + 1 < M) ? offs[mB + 1] : T) : tA1;

        int nA = tA1 - tA0;
        int nB = tB1 - tB0;                     // 0 when !hasB

        float aA0=0,aA1=0,aA2=0,aA3=0,aA4=0,aA5=0,aA6=0,aA7=0;
        float aB0=0,aB1=0,aB2=0,aB3=0,aB4=0,aB5=0,aB6=0,aB7=0;

        int cA = tA0, cB = tB0;
        while (cA < tA1 || cB < tB1) {
            int nnA = tA1 - cA; nnA = (nnA > 64) ? 64 : nnA; if (nnA < 0) nnA = 0;
            int nnB = tB1 - cB; nnB = (nnB > 64) ? 64 : nnB; if (nnB < 0) nnB = 0;
            int idxA = (lane < nnA) ? fs[cA + lane] : 0;
            int idxB = (lane < nnB) ? fs[cB + lane] : 0;

            int jA = 0, jB = 0;
            for (; jA + 8 <= nnA && jB + 8 <= nnB; jA += 8, jB += 8) {
                QSTEP2(idxA, jA, aA0,aA1,aA2,aA3,aA4,aA5,aA6,aA7);
                QSTEP2(idxB, jB, aB0,aB1,aB2,aB3,aB4,aB5,aB6,aB7);
            }
            for (; jA + 8 <= nnA; jA += 8)
                QSTEP2(idxA, jA, aA0,aA1,aA2,aA3,aA4,aA5,aA6,aA7);
            for (; jB + 8 <= nnB; jB += 8)
                QSTEP2(idxB, jB, aB0,aB1,aB2,aB3,aB4,aB5,aB6,aB7);
            for (; jA + 4 <= nnA; jA += 4)
                QSTEP1(idxA, jA, aA0,aA1,aA2,aA3,aA4,aA5,aA6,aA7);
            for (; jB + 4 <= nnB; jB += 4)
                QSTEP1(idxB, jB, aB0,aB1,aB2,aB3,aB4,aB5,aB6,aB7);
            QTAIL(idxA, jA, nnA, aA0,aA1,aA2,aA3,aA4,aA5,aA6,aA7);
            QTAIL(idxB, jB, nnB, aB0,aB1,aB2,aB3,aB4,aB5,aB6,aB7);
            cA += nnA; cB += nnB;
        }

        // epilogue: quarter-merge + mean + one-hot score + online update
        {
            QFIN(aA0,aA1,aA2,aA3,aA4,aA5,aA6,aA7, nA);
            float pA; SELP(aA0,aA1,aA2,aA3,aA4,aA5,aA6,aA7, pA);
            ONLUPD(pA, aA0,aA1,aA2,aA3,aA4,aA5,aA6,aA7);
        }
        if (hasB) {
            QFIN(aB0,aB1,aB2,aB3,aB4,aB5,aB6,aB7, nB);
            float pB; SELP(aB0,aB1,aB2,aB3,aB4,aB5,aB6,aB7, pB);
            ONLUPD(pB, aB0,aB1,aB2,aB3,aB4,aB5,aB6,aB7);
        }
    }

    // ---- deposit per-wave state (lanes 0..15 own dims 8c..8c+7) ----
    if (lane < 16) {
        ((float4*)s_acc[wid])[c * 2]     = make_float4(z0, z1, z2, z3);
        ((float4*)s_acc[wid])[c * 2 + 1] = make_float4(z4, z5, z6, z7);
    }
    if (lane == 0) { s_stats[wid][0] = mx; s_stats[wid][1] = sum; }
    __syncthreads();

    // ---- 8-way online-softmax merge; one S-col per thread (tid<SPAD) ----
    if (tid < SPAD) {
        float Mx = -INFINITY;
        #pragma unroll
        for (int g = 0; g < NW; ++g) Mx = fmaxf(Mx, s_stats[g][0]);
        float Ssum = 0.f, be = 0.f;
        #pragma unroll
        for (int g = 0; g < NW; ++g) {
            float e = __expf(s_stats[g][0] - Mx);
            Ssum += s_stats[g][1] * e;
            be   += s_acc[g][tid] * e;
        }
        s_be[tid] = be * (1.0f / Ssum);
    }
    __syncthreads();

    // ---- output: out[b][k] = s_be[k], k < K (no projection) ----
    float* ob = out + (size_t)b * K;
    if (2 * tid + 1 < K) {
        ((float2*)ob)[tid] = make_float2(s_be[2*tid], s_be[2*tid+1]);
    } else if (2 * tid < K) {
        ob[2*tid] = s_be[2*tid];
    }
}

// ---------------------------------------------------------------------------
extern "C" void kernel_launch(void* const* d_in, const int* in_sizes, int n_in,
                              void* d_out, int out_size, void* d_ws, size_t ws_size,
                              hipStream_t stream) {
    const int*   feature_seq = (const int*)d_in[0];
    const int*   offset_seq  = (const int*)d_in[1];
    const int*   scope       = (const int*)d_in[2];
    const float* typeTensor  = (const float*)d_in[3];
    const float* word_emb    = (const float*)d_in[4];
    const float* linear_w    = (const float*)d_in[5];
    float* out = (float*)d_out;

    const int T = in_sizes[0];
    const int M = in_sizes[1];
    const int B = in_sizes[2] - 1;
    const int K = in_sizes[3] / B;       // 100
    const int D = in_sizes[5] / K;       // 256
    const int V = in_sizes[4] / D;       // 100000

    // workspace carve-up: type_idx + S (V * SPAD halves = 25.6 MB)
    char* w = (char*)d_ws;
    auto align256 = [](size_t x) { return (x + 255) & ~(size_t)255; };
    int*    type_idx = (int*)w;    w += align256((size_t)B * sizeof(int));
    __half* S        = (__half*)w; // V * SPAD halves

    // K1: argmax + S-GEMM (MFMA)
    {
        int nArgBlk  = (B + 3) / 4;
        int nStrips  = (V + 15) / 16;
        int nGemmBlk = (nStrips + 3) / 4;
        k_prep<<<nArgBlk + nGemmBlk, 256, 0, stream>>>(
            typeTensor, linear_w, word_emb, type_idx, S, B, K, D, V, nArgBlk);
    }
    // K2: fused mention mean-S + per-bag online softmax (direct K-dim output)
    {
        k_fused<<<B, 512, 0, stream>>>(feature_seq, offset_seq, scope, type_idx,
                                       S, out, B, M, T, K);
    }
}

// Round 10
// 245.745 us; speedup vs baseline: 1.2407x; 1.0363x over previous
//
#include <hip/hip_runtime.h>
#include <hip/hip_fp16.h>
#include <math.h>

#define WAVE  64
#define SPAD  128    // padded score cols (K=100 -> 128)
#define NW    8      // waves per block in k_fused
#define WCOLS 112    // padded W^T cols staged fp16 (7 col-tiles of 16)

typedef float    f32x4 __attribute__((ext_vector_type(4)));
typedef _Float16 f16x8 __attribute__((ext_vector_type(8)));

#define MFMA16 __builtin_amdgcn_mfma_f32_16x16x32_f16

__device__ __forceinline__ f16x8 cvt8(float4 a, float4 b) {
    f16x8 r;
    r[0]=(_Float16)a.x; r[1]=(_Float16)a.y; r[2]=(_Float16)a.z; r[3]=(_Float16)a.w;
    r[4]=(_Float16)b.x; r[5]=(_Float16)b.y; r[6]=(_Float16)b.z; r[7]=(_Float16)b.w;
    return r;
}

// fp32 convert-and-accumulate of one 16B chunk (8 halves), weighted
#define ACC8T(qq,s,A0,A1,A2,A3,A4,A5,A6,A7) {                                \
    const __half2* hh_ = (const __half2*)&(qq);                              \
    float2 f0_=__half22float2(hh_[0]), f1_=__half22float2(hh_[1]);           \
    float2 f2_=__half22float2(hh_[2]), f3_=__half22float2(hh_[3]);           \
    A0+=(s)*f0_.x; A1+=(s)*f0_.y; A2+=(s)*f1_.x; A3+=(s)*f1_.y;              \
    A4+=(s)*f2_.x; A5+=(s)*f2_.y; A6+=(s)*f3_.x; A7+=(s)*f3_.y; }

// depth-1 fp16 pair-add over 2 token-rows, then one fp32 convert-add
#define TREE2T(qa,qb,A0,A1,A2,A3,A4,A5,A6,A7) {                              \
    const __half2* p0_ = (const __half2*)&(qa);                              \
    const __half2* p1_ = (const __half2*)&(qb);                              \
    __half2 s0_=__hadd2(p0_[0],p1_[0]);                                      \
    __half2 s1_=__hadd2(p0_[1],p1_[1]);                                      \
    __half2 s2_=__hadd2(p0_[2],p1_[2]);                                      \
    __half2 s3_=__hadd2(p0_[3],p1_[3]);                                      \
    float2 f0_=__half22float2(s0_), f1_=__half22float2(s1_);                 \
    float2 f2_=__half22float2(s2_), f3_=__half22float2(s3_);                 \
    A0+=f0_.x; A1+=f0_.y; A2+=f1_.x; A3+=f1_.y;                              \
    A4+=f2_.x; A5+=f2_.y; A6+=f3_.x; A7+=f3_.y; }

// ---- quarter-group (16-lane) S-row gather steps: 4 tokens per wave-load ----
#define QSTEP2(idxv,j0,A0,A1,A2,A3,A4,A5,A6,A7) {                            \
    int r0_ = __shfl(idxv, (j0) + qtr);                                      \
    int r1_ = __shfl(idxv, (j0) + 4 + qtr);                                  \
    float4 q0_ = S16[(size_t)r0_ * 16 + c];                                  \
    float4 q1_ = S16[(size_t)r1_ * 16 + c];                                  \
    TREE2T(q0_, q1_, A0,A1,A2,A3,A4,A5,A6,A7); }
#define QSTEP1(idxv,j0,A0,A1,A2,A3,A4,A5,A6,A7) {                            \
    int r0_ = __shfl(idxv, (j0) + qtr);                                      \
    float4 q0_ = S16[(size_t)r0_ * 16 + c];                                  \
    ACC8T(q0_, 1.0f, A0,A1,A2,A3,A4,A5,A6,A7); }
#define QTAIL(idxv,jv,nn,A0,A1,A2,A3,A4,A5,A6,A7) if ((jv) < (nn)) {         \
    int srcl_ = (jv) + qtr;                                                  \
    int rr_ = __shfl(idxv, (srcl_ < (nn)) ? srcl_ : ((nn) - 1));             \
    float s_ = (srcl_ < (nn)) ? 1.0f : 0.0f;                                 \
    float4 q_ = S16[(size_t)rr_ * 16 + c];                                   \
    ACC8T(q_, s_, A0,A1,A2,A3,A4,A5,A6,A7); }

// quarter-merge (xor 16,32) + mean
#define QFIN(A0,A1,A2,A3,A4,A5,A6,A7,nv) {                                   \
    A0+=__shfl_xor(A0,16); A1+=__shfl_xor(A1,16);                            \
    A2+=__shfl_xor(A2,16); A3+=__shfl_xor(A3,16);                            \
    A4+=__shfl_xor(A4,16); A5+=__shfl_xor(A5,16);                            \
    A6+=__shfl_xor(A6,16); A7+=__shfl_xor(A7,16);                            \
    A0+=__shfl_xor(A0,32); A1+=__shfl_xor(A1,32);                            \
    A2+=__shfl_xor(A2,32); A3+=__shfl_xor(A3,32);                            \
    A4+=__shfl_xor(A4,32); A5+=__shfl_xor(A5,32);                            \
    A6+=__shfl_xor(A6,32); A7+=__shfl_xor(A7,32);                            \
    float inv_ = 1.0f/(float)(nv);                                           \
    A0*=inv_; A1*=inv_; A2*=inv_; A3*=inv_;                                  \
    A4*=inv_; A5*=inv_; A6*=inv_; A7*=inv_; }

// selected score = mean-S-row[rt] (one element pick + 16-lane reduce)
#define SELP(A0,A1,A2,A3,A4,A5,A6,A7,pvar) {                                 \
    float t_ = (rlo==0)?A0:(rlo==1)?A1:(rlo==2)?A2:(rlo==3)?A3:              \
               (rlo==4)?A4:(rlo==5)?A5:(rlo==6)?A6:A7;                       \
    pvar = (c == rhi) ? t_ : 0.0f;                                           \
    pvar += __shfl_xor(pvar,1); pvar += __shfl_xor(pvar,2);                  \
    pvar += __shfl_xor(pvar,4); pvar += __shfl_xor(pvar,8); }

// online-softmax update of (mx,sum,z0..z7)
#define ONLUPD(pv,A0,A1,A2,A3,A4,A5,A6,A7) {                                 \
    float nmx_=fmaxf(mx,pv);                                                 \
    float sc_=__expf(mx-nmx_), w_=__expf((pv)-nmx_);                         \
    sum=sum*sc_+w_;                                                          \
    z0=z0*sc_+w_*A0; z1=z1*sc_+w_*A1; z2=z2*sc_+w_*A2; z3=z3*sc_+w_*A3;      \
    z4=z4*sc_+w_*A4; z5=z5*sc_+w_*A5; z6=z6*sc_+w_*A6; z7=z7*sc_+w_*A7;      \
    mx=nmx_; }

// ---------------------------------------------------------------------------
// K0 (k_w): argmax + W^T fp32->fp16 to GLOBAL (wh[112][256], cols K..111
// zero). Separate launch so k_gemm blocks see wh ready (cross-block ordering
// inside one kernel is undefined). Tiny: ~2.2 MB read total.
// ---------------------------------------------------------------------------
__global__ __launch_bounds__(256) void k_w(const float* __restrict__ tt,
                                           const float* __restrict__ lw,
                                           int* __restrict__ type_idx,
                                           __half* __restrict__ wh,
                                           int B, int K, int D, int nArgBlk) {
    int bx = blockIdx.x;
    if (bx < nArgBlk) {
        int wid  = threadIdx.x >> 6;
        int lane = threadIdx.x & 63;
        int b = bx * 4 + wid;
        if (b >= B) return;
        float best = -INFINITY;
        int   bi   = 0x7fffffff;
        for (int k = lane; k < K; k += WAVE) {
            float v = tt[(size_t)b * K + k];
            if (v > best) { best = v; bi = k; }
        }
        for (int off = 32; off > 0; off >>= 1) {
            float ov = __shfl_down(best, off);
            int   oi = __shfl_down(bi, off);
            if (ov > best || (ov == best && oi < bi)) { best = ov; bi = oi; }
        }
        if (lane == 0) type_idx[b] = bi;
    } else {
        int e = ((bx - nArgBlk) * 256 + (int)threadIdx.x) * 4;
        int total = WCOLS * 256;
        #pragma unroll
        for (int i = 0; i < 4; ++i) {
            int idx = e + i;
            if (idx >= total) break;
            int col = idx >> 8;
            int k   = idx & 255;
            wh[idx] = (col < K) ? __float2half(lw[(size_t)col * D + k])
                                : __half(0.0f);
        }
    }
}

// ---------------------------------------------------------------------------
// K1 (k_gemm): S = we @ W^T fp16 [V][SPAD] via MFMA 16x16x32_f16.
// R9 was latency-bound (MfmaUtil 2.5%, occ 17.8%): every block re-staged a
// 59KB W^T LDS tile (28-iter staging + barrier, 2 blocks/CU). v2: NO LDS —
// B-frags read directly from global wh (57KB, L2-resident, broadcast; each
// wave instruction = 16 fully-used 64B sectors). Wave processes a PAIR of
// 16-row strips so each bf read feeds 2 MFMAs (bf L2 traffic halved), with
// A-loads software-pipelined one k-group (2 k-chunks) ahead. MFMA math,
// fragment maps, and store pattern identical to R9 (hardware-verified).
// ---------------------------------------------------------------------------
__global__ __launch_bounds__(256) void k_gemm(const float* __restrict__ we,
                                              const __half* __restrict__ wh,
                                              __half* __restrict__ S,
                                              int V) {
    int tid  = threadIdx.x;
    int wid  = tid >> 6;
    int lane = tid & 63;
    int npair = V >> 5;                      // 3125 (V = 100000)
    int pair  = blockIdx.x * 4 + wid;
    if (pair >= npair) return;
    int rb   = pair << 5;                    // 32 rows: strips rb, rb+16
    int r16  = lane & 15;
    int kq   = (lane >> 4) << 1;             // float4 offset of my k-group
    int kbase = (lane >> 4) * 8;             // half offset of my k-group

    const float4* wA = (const float4*)we + (size_t)(rb + r16) * 64;
    const float4* wB = (const float4*)we + (size_t)(rb + 16 + r16) * 64;
    const _Float16* whh = (const _Float16*)wh;

    f32x4 accA[7], accB[7];
    #pragma unroll
    for (int ct = 0; ct < 7; ++ct) {
        accA[ct] = (f32x4){0.f,0.f,0.f,0.f};
        accB[ct] = (f32x4){0.f,0.f,0.f,0.f};
    }

    // preload k-group 0 (kc=0,1) for both strips
    float4 bA0=wA[kq], bA1=wA[kq+1], bA2=wA[kq+8], bA3=wA[kq+9];
    float4 bB0=wB[kq], bB1=wB[kq+1], bB2=wB[kq+8], bB3=wB[kq+9];

    #pragma unroll
    for (int g = 0; g < 4; ++g) {            // k-group = 2 k-chunks of 32
        float4 nA0,nA1,nA2,nA3,nB0,nB1,nB2,nB3;
        if (g < 3) {                         // prefetch next group
            int o = kq + (g + 1) * 16;
            nA0=wA[o]; nA1=wA[o+1]; nA2=wA[o+8]; nA3=wA[o+9];
            nB0=wB[o]; nB1=wB[o+1]; nB2=wB[o+8]; nB3=wB[o+9];
        }
        f16x8 aAe = cvt8(bA0,bA1), aAo = cvt8(bA2,bA3);
        f16x8 aBe = cvt8(bB0,bB1), aBo = cvt8(bB2,bB3);
        int ke = g * 64 + kbase;             // halves; odd chunk at +32
        #pragma unroll
        for (int ct = 0; ct < 7; ++ct) {
            const _Float16* wrow = whh + (size_t)(ct * 16 + r16) * 256;
            f16x8 be = *(const f16x8*)(wrow + ke);
            f16x8 bo = *(const f16x8*)(wrow + ke + 32);
            accA[ct] = MFMA16(aAe, be, accA[ct], 0, 0, 0);
            accB[ct] = MFMA16(aBe, be, accB[ct], 0, 0, 0);
            accA[ct] = MFMA16(aAo, bo, accA[ct], 0, 0, 0);
            accB[ct] = MFMA16(aBo, bo, accB[ct], 0, 0, 0);
        }
        if (g < 3) {
            bA0=nA0; bA1=nA1; bA2=nA2; bA3=nA3;
            bB0=nB0; bB1=nB1; bB2=nB2; bB3=nB3;
        }
    }

    // stores: lane covers rows rb(+16)+rofs+i, col ct*16+r16 (m89 C/D map)
    int rofs = (lane >> 4) * 4;
    #pragma unroll
    for (int ct = 0; ct < 7; ++ct) {
        #pragma unroll
        for (int i = 0; i < 4; ++i) {
            S[(size_t)(rb + rofs + i) * SPAD + ct * 16 + r16] =
                __float2half(accA[ct][i]);
            S[(size_t)(rb + 16 + rofs + i) * SPAD + ct * 16 + r16] =
                __float2half(accB[ct][i]);
        }
    }
    #pragma unroll
    for (int i = 0; i < 4; ++i) {            // zero pad cols 112..127
        S[(size_t)(rb + rofs + i) * SPAD + 112 + r16] = __half(0.0f);
        S[(size_t)(rb + 16 + rofs + i) * SPAD + 112 + r16] = __half(0.0f);
    }
}

// ---------------------------------------------------------------------------
// K2 (fused): UNCHANGED (R8/R9, ~50us). One block (512 thr = 8 waves) per
// bag; wave owns two adjacent mention chains (16 chains/bag, zero
// divergence). Gathers 256B S-rows (quarter-group: 4 tokens/wave-load).
// sel = one-hot pick from mean-S-row; out = online-softmax accumulation of
// mean-S-rows -- no final projection.
// ---------------------------------------------------------------------------
__global__ __launch_bounds__(512, 8) void k_fused(const int* __restrict__ fs,
                                                  const int* __restrict__ offs,
                                                  const int* __restrict__ scope,
                                                  const int* __restrict__ type_idx,
                                                  const __half* __restrict__ S,
                                                  float* __restrict__ out,
                                                  int B, int M, int T, int K) {
    __shared__ float s_acc[NW][SPAD];
    __shared__ float s_stats[NW][2];
    __shared__ float s_be[SPAD];

    int b    = blockIdx.x;
    int tid  = threadIdx.x;
    int wid  = tid >> 6;
    int lane = tid & 63;
    int c    = lane & 15;     // 16B chunk within 256B S-row
    int qtr  = lane >> 4;     // quarter: token j+qtr of each 4-token step

    int m0 = scope[b];
    int m1 = scope[b + 1];
    int rt  = type_idx[b];
    int rhi = rt >> 3, rlo = rt & 7;

    const float4* S16 = (const float4*)S;   // 16 chunks per 256B row

    float mx = -INFINITY, sum = 0.f;
    float z0=0,z1=0,z2=0,z3=0,z4=0,z5=0,z6=0,z7=0;

    for (int mA = m0 + wid * 2; mA < m1; mA += 2 * NW) {
        int mB = mA + 1;
        bool hasB = (mB < m1);                  // wave-uniform

        int tA0 = offs[mA];
        int tA1 = (mA + 1 < M) ? offs[mA + 1] : T;
        int tB0 = tA1;                          // offs[mB] == tA1 when hasB
        int tB1 = hasB ? ((mB + 1 < M) ? offs[mB + 1] : T) : tA1;

        int nA = tA1 - tA0;
        int nB = tB1 - tB0;                     // 0 when !hasB

        float aA0=0,aA1=0,aA2=0,aA3=0,aA4=0,aA5=0,aA6=0,aA7=0;
        float aB0=0,aB1=0,aB2=0,aB3=0,aB4=0,aB5=0,aB6=0,aB7=0;

        int cA = tA0, cB = tB0;
        while (cA < tA1 || cB < tB1) {
            int nnA = tA1 - cA; nnA = (nnA > 64) ? 64 : nnA; if (nnA < 0) nnA = 0;
            int nnB = tB1 - cB; nnB = (nnB > 64) ? 64 : nnB; if (nnB < 0) nnB = 0;
            int idxA = (lane < nnA) ? fs[cA + lane] : 0;
            int idxB = (lane < nnB) ? fs[cB + lane] : 0;

            int jA = 0, jB = 0;
            for (; jA + 8 <= nnA && jB + 8 <= nnB; jA += 8, jB += 8) {
                QSTEP2(idxA, jA, aA0,aA1,aA2,aA3,aA4,aA5,aA6,aA7);
                QSTEP2(idxB, jB, aB0,aB1,aB2,aB3,aB4,aB5,aB6,aB7);
            }
            for (; jA + 8 <= nnA; jA += 8)
                QSTEP2(idxA, jA, aA0,aA1,aA2,aA3,aA4,aA5,aA6,aA7);
            for (; jB + 8 <= nnB; jB += 8)
                QSTEP2(idxB, jB, aB0,aB1,aB2,aB3,aB4,aB5,aB6,aB7);
            for (; jA + 4 <= nnA; jA += 4)
                QSTEP1(idxA, jA, aA0,aA1,aA2,aA3,aA4,aA5,aA6,aA7);
            for (; jB + 4 <= nnB; jB += 4)
                QSTEP1(idxB, jB, aB0,aB1,aB2,aB3,aB4,aB5,aB6,aB7);
            QTAIL(idxA, jA, nnA, aA0,aA1,aA2,aA3,aA4,aA5,aA6,aA7);
            QTAIL(idxB, jB, nnB, aB0,aB1,aB2,aB3,aB4,aB5,aB6,aB7);
            cA += nnA; cB += nnB;
        }

        // epilogue: quarter-merge + mean + one-hot score + online update
        {
            QFIN(aA0,aA1,aA2,aA3,aA4,aA5,aA6,aA7, nA);
            float pA; SELP(aA0,aA1,aA2,aA3,aA4,aA5,aA6,aA7, pA);
            ONLUPD(pA, aA0,aA1,aA2,aA3,aA4,aA5,aA6,aA7);
        }
        if (hasB) {
            QFIN(aB0,aB1,aB2,aB3,aB4,aB5,aB6,aB7, nB);
            float pB; SELP(aB0,aB1,aB2,aB3,aB4,aB5,aB6,aB7, pB);
            ONLUPD(pB, aB0,aB1,aB2,aB3,aB4,aB5,aB6,aB7);
        }
    }

    // ---- deposit per-wave state (lanes 0..15 own dims 8c..8c+7) ----
    if (lane < 16) {
        ((float4*)s_acc[wid])[c * 2]     = make_float4(z0, z1, z2, z3);
        ((float4*)s_acc[wid])[c * 2 + 1] = make_float4(z4, z5, z6, z7);
    }
    if (lane == 0) { s_stats[wid][0] = mx; s_stats[wid][1] = sum; }
    __syncthreads();

    // ---- 8-way online-softmax merge; one S-col per thread (tid<SPAD) ----
    if (tid < SPAD) {
        float Mx = -INFINITY;
        #pragma unroll
        for (int g = 0; g < NW; ++g) Mx = fmaxf(Mx, s_stats[g][0]);
        float Ssum = 0.f, be = 0.f;
        #pragma unroll
        for (int g = 0; g < NW; ++g) {
            float e = __expf(s_stats[g][0] - Mx);
            Ssum += s_stats[g][1] * e;
            be   += s_acc[g][tid] * e;
        }
        s_be[tid] = be * (1.0f / Ssum);
    }
    __syncthreads();

    // ---- output: out[b][k] = s_be[k], k < K (no projection) ----
    float* ob = out + (size_t)b * K;
    if (2 * tid + 1 < K) {
        ((float2*)ob)[tid] = make_float2(s_be[2*tid], s_be[2*tid+1]);
    } else if (2 * tid < K) {
        ob[2*tid] = s_be[2*tid];
    }
}

// ---------------------------------------------------------------------------
extern "C" void kernel_launch(void* const* d_in, const int* in_sizes, int n_in,
                              void* d_out, int out_size, void* d_ws, size_t ws_size,
                              hipStream_t stream) {
    const int*   feature_seq = (const int*)d_in[0];
    const int*   offset_seq  = (const int*)d_in[1];
    const int*   scope       = (const int*)d_in[2];
    const float* typeTensor  = (const float*)d_in[3];
    const float* word_emb    = (const float*)d_in[4];
    const float* linear_w    = (const float*)d_in[5];
    float* out = (float*)d_out;

    const int T = in_sizes[0];
    const int M = in_sizes[1];
    const int B = in_sizes[2] - 1;
    const int K = in_sizes[3] / B;       // 100
    const int D = in_sizes[5] / K;       // 256
    const int V = in_sizes[4] / D;       // 100000

    // workspace carve-up: type_idx + wh (fp16 W^T) + S (25.6 MB)
    char* w = (char*)d_ws;
    auto align256 = [](size_t x) { return (x + 255) & ~(size_t)255; };
    int*    type_idx = (int*)w;    w += align256((size_t)B * sizeof(int));
    __half* wh       = (__half*)w; w += align256((size_t)WCOLS * 256 * sizeof(__half));
    __half* S        = (__half*)w; // V * SPAD halves

    // K0: argmax + W^T fp16 convert (ordering barrier = launch boundary)
    {
        int nArgBlk = (B + 3) / 4;
        int nWBlk   = (WCOLS * 256 + 1023) / 1024;
        k_w<<<nArgBlk + nWBlk, 256, 0, stream>>>(
            typeTensor, linear_w, type_idx, wh, B, K, D, nArgBlk);
    }
    // K1: S-GEMM (MFMA, LDS-free, strip-pair waves)
    {
        int nPair = (V + 31) / 32;
        int nBlk  = (nPair + 3) / 4;
        k_gemm<<<nBlk, 256, 0, stream>>>(word_emb, wh, S, V);
    }
    // K2: fused mention mean-S + per-bag online softmax (direct K-dim output)
    {
        k_fused<<<B, 512, 0, stream>>>(feature_seq, offset_seq, scope, type_idx,
                                       S, out, B, M, T, K);
    }
}